// Round 8
// baseline (451.422 us; speedup 1.0000x reference)
//
#include <hip/hip_runtime.h>
#include <hip/hip_bf16.h>
#include <math.h>

#define N_NODES 20000
#define N_EDGES 320000

#define INV1   0.31622776601683794f   // 1/sqrt(10)
#define SC2    0.1f                   // 1/sqrt(100)
#define IS3    0.5773502691896258f    // 1/sqrt(3)
#define C_S    0.3826834323650898f    // sin(pi/8)
#define C_X    0.9238795325112867f    // cos(pi/8)
#define INV64  0.125f                 // 1/sqrt(64)
#define INVLO  0.08838834764831845f   // 1/sqrt(128)

typedef short     short8 __attribute__((ext_vector_type(8)));
typedef float     f32x4  __attribute__((ext_vector_type(4)));

__device__ __forceinline__ float silu_f(float x) {
    return x / (1.0f + expf(-x));
}
__device__ __forceinline__ unsigned short f2bf(float x) {
    __hip_bfloat16 h = __float2bfloat16(x);
    return *reinterpret_cast<unsigned short*>(&h);
}
__device__ __forceinline__ float bf2f(unsigned short u) {
    __hip_bfloat16 h;
    *reinterpret_cast<unsigned short*>(&h) = u;
    return __bfloat162float(h);
}

// ---------------- node pre-pass: fvb[n][64] = ushort4 bf16, out = c_s * m ---
// (byte-identical to the R7 passing version)
__global__ __launch_bounds__(256) void k_node_in(
    const float* __restrict__ ni, const float* __restrict__ attr,
    const float* __restrict__ deg,
    const float* __restrict__ Wli0, const float* __restrict__ Wli1,
    const float* __restrict__ Wlm0, const float* __restrict__ Wlm1,
    ushort4* __restrict__ fvb, float* __restrict__ out)
{
    __shared__ float raw[4][256];
    const int wave = threadIdx.x >> 6;
    const int lane = threadIdx.x & 63;
    const int n = blockIdx.x * 4 + wave;

    const float* row = ni + (size_t)n * 256;
    raw[wave][lane      ] = row[lane      ];
    raw[wave][lane + 64 ] = row[lane + 64 ];
    raw[wave][lane + 128] = row[lane + 128];
    raw[wave][lane + 192] = row[lane + 192];
    __syncthreads();

    float f0 = 0.f, m0 = 0.f;
    float f1x = 0.f, f1y = 0.f, f1z = 0.f;
    float m1x = 0.f, m1y = 0.f, m1z = 0.f;
    #pragma unroll 4
    for (int t = 0; t < 64; ++t) {
        float xs  = raw[wave][t];
        float xv0 = raw[wave][64 + t*3    ];
        float xv1 = raw[wave][64 + t*3 + 1];
        float xv2 = raw[wave][64 + t*3 + 2];
        float a0 = Wli0[t*64 + lane];
        float a1 = Wli1[t*64 + lane];
        float b0 = Wlm0[t*64 + lane];
        float b1 = Wlm1[t*64 + lane];
        f0  += xs  * a0;   m0  += xs  * b0;
        f1x += xv0 * a1;   f1y += xv1 * a1;   f1z += xv2 * a1;
        m1x += xv0 * b1;   m1y += xv1 * b1;   m1z += xv2 * b1;
    }

    const float a   = attr[n] * INV64;
    const float dis = 1.0f / sqrtf(deg[n]);
    const float fa  = a * dis;

    ushort4 pk;
    pk.x = f2bf(f0  * fa);
    pk.y = f2bf(f1x * fa);
    pk.z = f2bf(f1y * fa);
    pk.w = f2bf(f1z * fa);
    fvb[(size_t)n * 64 + lane] = pk;

    float* orow = out + (size_t)n * 256;
    orow[lane] = C_S * m0 * a;
    orow[64 + lane*3    ] = C_S * m1x * a;
    orow[64 + lane*3 + 1] = C_S * m1y * a;
    orow[64 + lane*3 + 2] = C_S * m1z * a;
}

// ---------------- weight prep: w2t[256][128], w1t[112][32] (bf16, scaled) ---
__global__ __launch_bounds__(256) void k_w2t(
    const float* __restrict__ W2, const float* __restrict__ W1,
    unsigned short* __restrict__ w2t, unsigned short* __restrict__ w1t)
{
    const int i = blockIdx.x * 256 + threadIdx.x;
    if (i < 32768) {
        const int n = i >> 7, k = i & 127;
        w2t[i] = (k < 100) ? f2bf(W2[k*256 + n] * SC2) : (unsigned short)0;
    } else if (i < 32768 + 3584) {
        const int j = i - 32768;
        const int n = j >> 5, k = j & 31;
        w1t[j] = (k < 10 && n < 100) ? f2bf(W1[k*100 + n] * INV1)
                                     : (unsigned short)0;
    }
}

// ---------------- counting sort by dst + sorted edge data -------------------
__global__ __launch_bounds__(256) void k_hist(const int* __restrict__ edst,
                                              int* __restrict__ hist) {
    const int e = blockIdx.x * 256 + threadIdx.x;
    if (e < N_EDGES) atomicAdd(&hist[edst[e]], 1);
}

__global__ __launch_bounds__(1024) void k_scan(const int* __restrict__ hist,
                                               int* __restrict__ starts,
                                               int* __restrict__ cursor) {
    __shared__ int part[1024];
    const int t = threadIdx.x;
    const int C = 20;
    const int base = t * C;
    int s = 0;
    for (int i = 0; i < C; ++i) {
        const int idx = base + i;
        if (idx < N_NODES) s += hist[idx];
    }
    part[t] = s;
    __syncthreads();
    for (int off = 1; off < 1024; off <<= 1) {
        int v = (t >= off) ? part[t - off] : 0;
        __syncthreads();
        part[t] += v;
        __syncthreads();
    }
    int run = part[t] - s;
    for (int i = 0; i < C; ++i) {
        const int idx = base + i;
        if (idx < N_NODES) {
            starts[idx] = run;
            cursor[idx] = run;
            run += hist[idx];
        }
    }
    if (t == 1023) starts[N_NODES] = N_EDGES;
}

__global__ __launch_bounds__(256) void k_scatter(
    const int* __restrict__ esrc, const int* __restrict__ edst,
    const float4* __restrict__ eattr4, const float* __restrict__ elen,
    int* __restrict__ cursor, int* __restrict__ esrc_s,
    float4* __restrict__ eattrs, unsigned short* __restrict__ elen_sb)
{
    const int e = blockIdx.x * 256 + threadIdx.x;
    if (e < N_EDGES) {
        const int p = atomicAdd(&cursor[edst[e]], 1);
        esrc_s[p] = esrc[e];
        eattrs[p] = eattr4[e];
        const float* el = elen + (size_t)e * 10;
        unsigned short v[32];
        #pragma unroll
        for (int b = 0; b < 10; ++b) v[b] = f2bf(el[b]);
        #pragma unroll
        for (int b = 10; b < 32; ++b) v[b] = 0;
        short8* dst = (short8*)(elen_sb + (size_t)p * 32);
        #pragma unroll
        for (int s = 0; s < 4; ++s) {
            short8 pk;
            #pragma unroll
            for (int j = 0; j < 8; ++j) pk[j] = (short)v[s*8 + j];
            dst[s] = pk;
        }
    }
}

// ---------------- edge MLP, MFMA, sorted in/out, interleaved ew -------------
// (byte-identical to the R7 passing version)
__global__ __launch_bounds__(256, 4) void k_mlp(
    const unsigned short* __restrict__ elen_sb,
    const unsigned short* __restrict__ w1t,
    const unsigned short* __restrict__ w2t,
    unsigned short* __restrict__ ew)
{
    __shared__ unsigned short Hs[128 * 136];   // [e][k] stride 136
    const int t    = threadIdx.x;
    const int w    = t >> 6;
    const int lane = t & 63;
    const int m15  = lane & 15;
    const int q    = lane >> 4;
    const int eb   = w * 32;
    const int e0   = blockIdx.x * 128;

    {
        const int r = eb + (lane >> 1);
        const int c = 112 + (lane & 1) * 8;
        short8 z = {0,0,0,0,0,0,0,0};
        *(short8*)&Hs[r*136 + c] = z;
    }

    short8 xa0 = *(const short8*)(elen_sb + (size_t)(e0 + eb      + m15)*32 + q*8);
    short8 xa1 = *(const short8*)(elen_sb + (size_t)(e0 + eb + 16 + m15)*32 + q*8);

    for (int nt = 0; nt < 7; ++nt) {
        short8 bw = *(const short8*)(w1t + (nt*16 + m15)*32 + q*8);
        f32x4 z4 = {0.f, 0.f, 0.f, 0.f};
        f32x4 h0 = __builtin_amdgcn_mfma_f32_16x16x32_bf16(xa0, bw, z4, 0, 0, 0);
        f32x4 h1 = __builtin_amdgcn_mfma_f32_16x16x32_bf16(xa1, bw, z4, 0, 0, 0);
        #pragma unroll
        for (int r = 0; r < 4; ++r) {
            Hs[(eb      + q*4 + r)*136 + nt*16 + m15] = f2bf(silu_f(h0[r]));
            Hs[(eb + 16 + q*4 + r)*136 + nt*16 + m15] = f2bf(silu_f(h1[r]));
        }
    }

    short8 A0[4], A1[4];
    #pragma unroll
    for (int s = 0; s < 4; ++s) {
        A0[s] = *(const short8*)&Hs[(eb      + m15)*136 + s*32 + q*8];
        A1[s] = *(const short8*)&Hs[(eb + 16 + m15)*136 + s*32 + q*8];
    }

    unsigned short* stg = &Hs[eb * 136];
    unsigned short* gb2 = ew + (size_t)(e0 + eb) * 256;
    #pragma unroll
    for (int half = 0; half < 2; ++half) {
        for (int nt8 = 0; nt8 < 8; ++nt8) {
            const int nt = half*8 + nt8;
            f32x4 c0 = {0.f,0.f,0.f,0.f}, c1 = {0.f,0.f,0.f,0.f};
            const unsigned short* bp = w2t + ((size_t)(nt*16 + m15) << 7);
            #pragma unroll
            for (int s = 0; s < 4; ++s) {
                short8 B = *(const short8*)(bp + s*32 + q*8);
                c0 = __builtin_amdgcn_mfma_f32_16x16x32_bf16(A0[s], B, c0, 0, 0, 0);
                c1 = __builtin_amdgcn_mfma_f32_16x16x32_bf16(A1[s], B, c1, 0, 0, 0);
            }
            #pragma unroll
            for (int r = 0; r < 4; ++r) {
                stg[(     q*4 + r)*136 + nt8*16 + m15] = f2bf(c0[r]);
                stg[(16 + q*4 + r)*136 + nt8*16 + m15] = f2bf(c1[r]);
            }
        }
        for (int r = 0; r < 32; ++r) {
            const unsigned int v =
                (unsigned int)stg[r*136 + lane] |
                ((unsigned int)stg[r*136 + 64 + lane] << 16);
            *(unsigned int*)(gb2 + (size_t)r*256 + lane*4 + half*2) = v;
        }
    }
}

// ---------------- per-dst edge accumulation ONLY (prefetch-8 pipeline) ------
// acc[n][128] ushort4-bf16: [lane]=(sA,sB*IS3,vA0,vB0), [64+lane]=(vA1,vB1,vA2,vB2)
// Write-once per node (no memset; zero-edge nodes write zeros).
__global__ __launch_bounds__(256) void k_gather2(
    const int* __restrict__ starts, const int* __restrict__ esrc_s,
    const float4* __restrict__ eattrs, const unsigned short* __restrict__ ew,
    const ushort4* __restrict__ fvb, ushort4* __restrict__ acc)
{
    const int wave = threadIdx.x >> 6;
    const int lane = threadIdx.x & 63;
    const int n = blockIdx.x * 4 + wave;

    const int beg = starts[n], end = starts[n + 1];
    float sA=0.f, sB=0.f;
    float vA0=0.f, vA1=0.f, vA2=0.f;
    float vB0=0.f, vB1=0.f, vB2=0.f;

    for (int base = beg; base < end; base += 64) {
        const int cnt = min(64, end - base);
        int    srcv = 0;
        float4 eav  = make_float4(0.f, 0.f, 0.f, 0.f);
        if (lane < cnt) {
            srcv = esrc_s[base + lane];
            eav  = eattrs[base + lane];
        }
        for (int j0 = 0; j0 < cnt; j0 += 8) {
            const int m = min(8, cnt - j0);   // wave-uniform
            ushort4 wv[8], gv[8];
            #pragma unroll
            for (int i = 0; i < 8; ++i) {
                if (i < m) {
                    const int src = __shfl(srcv, j0 + i);
                    wv[i] = *(const ushort4*)(ew + (size_t)(base + j0 + i)*256 + lane*4);
                    gv[i] = fvb[(size_t)src * 64 + lane];
                }
            }
            #pragma unroll
            for (int i = 0; i < 8; ++i) {
                if (i < m) {
                    const float y0  = __shfl(eav.x, j0 + i);
                    const float y10 = __shfl(eav.y, j0 + i);
                    const float y11 = __shfl(eav.z, j0 + i);
                    const float y12 = __shfl(eav.w, j0 + i);

                    const float wa = bf2f(wv[i].x);
                    const float wb = bf2f(wv[i].y);
                    const float wc = bf2f(wv[i].z);
                    const float wd = bf2f(wv[i].w);

                    const float g0  = bf2f(gv[i].x);
                    const float g10 = bf2f(gv[i].y);
                    const float g11 = bf2f(gv[i].z);
                    const float g12 = bf2f(gv[i].w);

                    const float dotv = g10*y10 + g11*y11 + g12*y12;
                    sA += wa * g0 * y0;
                    sB += wb * dotv;
                    const float t0 = wc * g0;
                    vA0 += t0 * y10;  vA1 += t0 * y11;  vA2 += t0 * y12;
                    const float t1 = wd * y0;
                    vB0 += t1 * g10;  vB1 += t1 * g11;  vB2 += t1 * g12;
                }
            }
        }
    }

    ushort4 p0, p1;
    p0.x = f2bf(sA);        p0.y = f2bf(sB * IS3);
    p0.z = f2bf(vA0);       p0.w = f2bf(vB0);
    p1.x = f2bf(vA1);       p1.y = f2bf(vB1);
    p1.z = f2bf(vA2);       p1.w = f2bf(vB2);
    acc[(size_t)n * 128 + lane]      = p0;
    acc[(size_t)n * 128 + 64 + lane] = p1;
}

// ---------------- node post-pass: deg scale + W_lo GEMM + epilogue ----------
// (R1's proven k_node_out shape, acc read adapted to bf16 ushort4)
__global__ __launch_bounds__(256) void k_node_out(
    const ushort4* __restrict__ acc, const float* __restrict__ attr,
    const float* __restrict__ deg, const float* __restrict__ Wlo0,
    const float* __restrict__ Wlo1, float* __restrict__ out)
{
    __shared__ float sm[4][512];
    const int wave = threadIdx.x >> 6;
    const int lane = threadIdx.x & 63;
    const int n = blockIdx.x * 4 + wave;

    const float dis = 1.0f / sqrtf(deg[n]);
    const ushort4 p0 = acc[(size_t)n * 128 + lane];
    const ushort4 p1 = acc[(size_t)n * 128 + 64 + lane];
    sm[wave][lane      ] = bf2f(p0.x) * dis;   // sA
    sm[wave][64  + lane] = bf2f(p0.y) * dis;   // sB*IS3
    sm[wave][128 + lane] = bf2f(p0.z) * dis;   // vA0
    sm[wave][192 + lane] = bf2f(p0.w) * dis;   // vB0
    sm[wave][256 + lane] = bf2f(p1.x) * dis;   // vA1
    sm[wave][320 + lane] = bf2f(p1.y) * dis;   // vB1
    sm[wave][384 + lane] = bf2f(p1.z) * dis;   // vA2
    sm[wave][448 + lane] = bf2f(p1.w) * dis;   // vB2
    __syncthreads();

    float o0 = 0.f, o1x = 0.f, o1y = 0.f, o1z = 0.f;
    #pragma unroll 4
    for (int c = 0; c < 128; ++c) {
        const float w0 = Wlo0[c*64 + lane];
        const float w1 = Wlo1[c*64 + lane];
        o0  += sm[wave][c]        * w0;
        o1x += sm[wave][128 + c]  * w1;
        o1y += sm[wave][256 + c]  * w1;
        o1z += sm[wave][384 + c]  * w1;
    }

    const float a = attr[n] * INVLO;
    float* orow = out + (size_t)n * 256;
    orow[lane] += C_X * o0 * a;
    orow[64 + lane*3    ] += C_X * o1x * a;
    orow[64 + lane*3 + 1] += C_X * o1y * a;
    orow[64 + lane*3 + 2] += C_X * o1z * a;
}

// ======================= fallback (round-1) path ============================
__global__ __launch_bounds__(256) void k_node_in_legacy(
    const float* __restrict__ ni, const float* __restrict__ attr,
    const float* __restrict__ deg,
    const float* __restrict__ Wli0, const float* __restrict__ Wli1,
    const float* __restrict__ Wlm0, const float* __restrict__ Wlm1,
    float* __restrict__ f, float* __restrict__ out)
{
    __shared__ float raw[4][256];
    const int wave = threadIdx.x >> 6;
    const int lane = threadIdx.x & 63;
    const int n = blockIdx.x * 4 + wave;

    const float* row = ni + (size_t)n * 256;
    raw[wave][lane      ] = row[lane      ];
    raw[wave][lane + 64 ] = row[lane + 64 ];
    raw[wave][lane + 128] = row[lane + 128];
    raw[wave][lane + 192] = row[lane + 192];
    __syncthreads();

    float f0 = 0.f, m0 = 0.f;
    float f1x = 0.f, f1y = 0.f, f1z = 0.f;
    float m1x = 0.f, m1y = 0.f, m1z = 0.f;
    for (int t = 0; t < 64; ++t) {
        float xs  = raw[wave][t];
        float xv0 = raw[wave][64 + t*3    ];
        float xv1 = raw[wave][64 + t*3 + 1];
        float xv2 = raw[wave][64 + t*3 + 2];
        float a0 = Wli0[t*64 + lane];
        float a1 = Wli1[t*64 + lane];
        float b0 = Wlm0[t*64 + lane];
        float b1 = Wlm1[t*64 + lane];
        f0  += xs  * a0;   m0  += xs  * b0;
        f1x += xv0 * a1;   f1y += xv1 * a1;   f1z += xv2 * a1;
        m1x += xv0 * b1;   m1y += xv1 * b1;   m1z += xv2 * b1;
    }

    const float a   = attr[n] * INV64;
    const float dis = 1.0f / sqrtf(deg[n]);
    const float fa  = a * dis;

    float* fr = f + (size_t)n * 256;
    fr[lane      ] = f0  * fa;
    fr[64  + lane] = f1x * fa;
    fr[128 + lane] = f1y * fa;
    fr[192 + lane] = f1z * fa;

    float* orow = out + (size_t)n * 256;
    orow[lane] = C_S * m0 * a;
    orow[64 + lane*3    ] = C_S * m1x * a;
    orow[64 + lane*3 + 1] = C_S * m1y * a;
    orow[64 + lane*3 + 2] = C_S * m1z * a;
}

__global__ __launch_bounds__(256) void k_edge_legacy(
    const float* __restrict__ eattr, const float* __restrict__ elen,
    const float* __restrict__ W1, const float* __restrict__ W2,
    const int* __restrict__ esrc, const int* __restrict__ edst,
    const float* __restrict__ f, float* __restrict__ acc)
{
    __shared__ float hsh[4][104];
    const int wave = threadIdx.x >> 6;
    const int lane = threadIdx.x & 63;
    const int e = blockIdx.x * 4 + wave;

    const float* el = elen + (size_t)e * 10;
    float elr[10];
    #pragma unroll
    for (int b = 0; b < 10; ++b) elr[b] = el[b];

    float a1 = 0.f;
    #pragma unroll
    for (int b = 0; b < 10; ++b) a1 += elr[b] * W1[b*100 + lane];
    hsh[wave][lane] = silu_f(a1 * INV1);
    if (lane < 36) {
        float a2 = 0.f;
        #pragma unroll
        for (int b = 0; b < 10; ++b) a2 += elr[b] * W1[b*100 + 64 + lane];
        hsh[wave][64 + lane] = silu_f(a2 * INV1);
    }
    __syncthreads();

    float wa = 0.f, wb = 0.f, wc = 0.f, wd = 0.f;
    for (int j = 0; j < 100; ++j) {
        float hj = hsh[wave][j];
        const float* wr = W2 + j*256;
        wa += hj * wr[lane      ];
        wb += hj * wr[64  + lane];
        wc += hj * wr[128 + lane];
        wd += hj * wr[192 + lane];
    }
    wa *= SC2; wb *= SC2; wc *= SC2; wd *= SC2;

    const int src = esrc[e];
    const int dst = edst[e];
    const float y0  = eattr[e*4 + 0];
    const float y10 = eattr[e*4 + 1];
    const float y11 = eattr[e*4 + 2];
    const float y12 = eattr[e*4 + 3];

    const float* fr = f + (size_t)src * 256;
    const float g0  = fr[lane      ];
    const float g10 = fr[64  + lane];
    const float g11 = fr[128 + lane];
    const float g12 = fr[192 + lane];

    const float dotv = g10*y10 + g11*y11 + g12*y12;

    float* ar = acc + (size_t)dst * 512;
    atomicAdd(ar + lane,                  wa * g0 * y0);
    atomicAdd(ar + 64 + lane,             wb * dotv * IS3);
    atomicAdd(ar + 128 +   0 + lane,      wc * g0 * y10);
    atomicAdd(ar + 128 + 128 + lane,      wc * g0 * y11);
    atomicAdd(ar + 128 + 256 + lane,      wc * g0 * y12);
    atomicAdd(ar + 128 +   0 + 64 + lane, wd * g10 * y0);
    atomicAdd(ar + 128 + 128 + 64 + lane, wd * g11 * y0);
    atomicAdd(ar + 128 + 256 + 64 + lane, wd * g12 * y0);
}

__global__ __launch_bounds__(256) void k_node_out_legacy(
    const float* __restrict__ acc, const float* __restrict__ attr,
    const float* __restrict__ deg, const float* __restrict__ Wlo0,
    const float* __restrict__ Wlo1, float* __restrict__ out)
{
    __shared__ float sm[4][512];
    const int wave = threadIdx.x >> 6;
    const int lane = threadIdx.x & 63;
    const int n = blockIdx.x * 4 + wave;

    const float dis = 1.0f / sqrtf(deg[n]);
    const float* ar = acc + (size_t)n * 512;
    for (int i = lane; i < 512; i += 64) sm[wave][i] = ar[i] * dis;
    __syncthreads();

    float o0 = 0.f, o1x = 0.f, o1y = 0.f, o1z = 0.f;
    for (int c = 0; c < 128; ++c) {
        float w0 = Wlo0[c*64 + lane];
        float w1 = Wlo1[c*64 + lane];
        o0  += sm[wave][c]        * w0;
        o1x += sm[wave][128 + c]  * w1;
        o1y += sm[wave][256 + c]  * w1;
        o1z += sm[wave][384 + c]  * w1;
    }

    const float a = attr[n] * INVLO;
    float* orow = out + (size_t)n * 256;
    orow[lane] += C_X * o0 * a;
    orow[64 + lane*3    ] += C_X * o1x * a;
    orow[64 + lane*3 + 1] += C_X * o1y * a;
    orow[64 + lane*3 + 2] += C_X * o1z * a;
}

// ============================================================================
extern "C" void kernel_launch(void* const* d_in, const int* in_sizes, int n_in,
                              void* d_out, int out_size, void* d_ws, size_t ws_size,
                              hipStream_t stream) {
    const float* ni    = (const float*)d_in[0];
    const float* attr  = (const float*)d_in[1];
    const float* deg   = (const float*)d_in[2];
    const float* eattr = (const float*)d_in[3];
    const float* elen  = (const float*)d_in[4];
    const float* Wli0  = (const float*)d_in[5];
    const float* Wli1  = (const float*)d_in[6];
    const float* Wlm0  = (const float*)d_in[7];
    const float* Wlm1  = (const float*)d_in[8];
    const float* Wm1   = (const float*)d_in[9];
    const float* Wm2   = (const float*)d_in[10];
    const float* Wlo0  = (const float*)d_in[11];
    const float* Wlo1  = (const float*)d_in[12];
    const int*   esrc  = (const int*)d_in[13];
    const int*   edst  = (const int*)d_in[14];

    float* out = (float*)d_out;

    // ws layout (fast path), 16 B-aligned sections
    char* wsb = (char*)d_ws;
    size_t off = 0;
    ushort4* fvb = (ushort4*)(wsb + off);               off += (size_t)N_NODES * 64 * 8;    // 10.24 MB
    unsigned short* ew = (unsigned short*)(wsb + off);  off += (size_t)N_EDGES * 256 * 2;   // 163.84 MB
    unsigned short* elen_sb = (unsigned short*)(wsb + off); off += (size_t)N_EDGES * 32 * 2;// 20.48 MB
    float4* eattrs = (float4*)(wsb + off);              off += (size_t)N_EDGES * 16;        // 5.12 MB
    int* esrc_s = (int*)(wsb + off);                    off += (size_t)N_EDGES * 4;         // 1.28 MB
    unsigned short* w2t = (unsigned short*)(wsb + off); off += 32768 * 2;
    unsigned short* w1t = (unsigned short*)(wsb + off); off += 3584 * 2;
    int* starts = (int*)(wsb + off);                    off += (size_t)(N_NODES + 4) * 4;
    int* hist   = (int*)(wsb + off);                    off += (size_t)N_NODES * 4;
    int* cursor = (int*)(wsb + off);                    off += (size_t)N_NODES * 4;
    const size_t need_fast = off;

    // acc (bf16, 20.48 MB) OVERLAYS elen_sb: elen_sb is dead after k_mlp,
    // and k_gather2 runs strictly after k_mlp on the same stream.
    ushort4* acc = (ushort4*)elen_sb;

    if (ws_size >= need_fast) {
        hipMemsetAsync(hist, 0, (size_t)N_NODES * sizeof(int), stream);
        k_node_in<<<N_NODES / 4, 256, 0, stream>>>(ni, attr, deg, Wli0, Wli1,
                                                   Wlm0, Wlm1, fvb, out);
        k_w2t    <<<144, 256, 0, stream>>>(Wm2, Wm1, w2t, w1t);
        k_hist   <<<N_EDGES / 256, 256, 0, stream>>>(edst, hist);
        k_scan   <<<1, 1024, 0, stream>>>(hist, starts, cursor);
        k_scatter<<<N_EDGES / 256, 256, 0, stream>>>(esrc, edst,
                                                     (const float4*)eattr, elen,
                                                     cursor, esrc_s, eattrs, elen_sb);
        k_mlp    <<<N_EDGES / 128, 256, 0, stream>>>(elen_sb, w1t, w2t, ew);
        k_gather2<<<N_NODES / 4, 256, 0, stream>>>(starts, esrc_s, eattrs, ew,
                                                   fvb, acc);
        k_node_out<<<N_NODES / 4, 256, 0, stream>>>(acc, attr, deg, Wlo0, Wlo1, out);
    } else {
        // fallback: round-1 atomic path (61.4 MB scratch)
        float* f   = (float*)d_ws;
        float* accf = f + (size_t)N_NODES * 256;
        hipMemsetAsync(accf, 0, (size_t)N_NODES * 512 * sizeof(float), stream);
        k_node_in_legacy<<<N_NODES / 4, 256, 0, stream>>>(ni, attr, deg, Wli0, Wli1,
                                                          Wlm0, Wlm1, f, out);
        k_edge_legacy<<<N_EDGES / 4, 256, 0, stream>>>(eattr, elen, Wm1, Wm2,
                                                       esrc, edst, f, accf);
        k_node_out_legacy<<<N_NODES / 4, 256, 0, stream>>>(accf, attr, deg,
                                                           Wlo0, Wlo1, out);
    }
}

// Round 9
// 413.569 us; speedup vs baseline: 1.0915x; 1.0915x over previous
//
#include <hip/hip_runtime.h>
#include <hip/hip_bf16.h>
#include <math.h>

#define N_NODES 20000
#define N_EDGES 320000

#define INV1   0.31622776601683794f   // 1/sqrt(10)
#define SC2    0.1f                   // 1/sqrt(100)
#define IS3    0.5773502691896258f    // 1/sqrt(3)
#define C_S    0.3826834323650898f    // sin(pi/8)
#define C_X    0.9238795325112867f    // cos(pi/8)
#define INV64  0.125f                 // 1/sqrt(64)
#define INVLO  0.08838834764831845f   // 1/sqrt(128)

typedef short     short8 __attribute__((ext_vector_type(8)));
typedef float     f32x4  __attribute__((ext_vector_type(4)));

__device__ __forceinline__ float silu_f(float x) {
    return x / (1.0f + expf(-x));
}
__device__ __forceinline__ unsigned short f2bf(float x) {
    __hip_bfloat16 h = __float2bfloat16(x);
    return *reinterpret_cast<unsigned short*>(&h);
}
__device__ __forceinline__ float bf2f(unsigned short u) {
    __hip_bfloat16 h;
    *reinterpret_cast<unsigned short*>(&h) = u;
    return __bfloat162float(h);
}

// ---------------- node pre-pass: fvb[n][64] = ushort4 bf16, out = c_s * m ---
// (byte-identical to the R7 passing version)
__global__ __launch_bounds__(256) void k_node_in(
    const float* __restrict__ ni, const float* __restrict__ attr,
    const float* __restrict__ deg,
    const float* __restrict__ Wli0, const float* __restrict__ Wli1,
    const float* __restrict__ Wlm0, const float* __restrict__ Wlm1,
    ushort4* __restrict__ fvb, float* __restrict__ out)
{
    __shared__ float raw[4][256];
    const int wave = threadIdx.x >> 6;
    const int lane = threadIdx.x & 63;
    const int n = blockIdx.x * 4 + wave;

    const float* row = ni + (size_t)n * 256;
    raw[wave][lane      ] = row[lane      ];
    raw[wave][lane + 64 ] = row[lane + 64 ];
    raw[wave][lane + 128] = row[lane + 128];
    raw[wave][lane + 192] = row[lane + 192];
    __syncthreads();

    float f0 = 0.f, m0 = 0.f;
    float f1x = 0.f, f1y = 0.f, f1z = 0.f;
    float m1x = 0.f, m1y = 0.f, m1z = 0.f;
    #pragma unroll 4
    for (int t = 0; t < 64; ++t) {
        float xs  = raw[wave][t];
        float xv0 = raw[wave][64 + t*3    ];
        float xv1 = raw[wave][64 + t*3 + 1];
        float xv2 = raw[wave][64 + t*3 + 2];
        float a0 = Wli0[t*64 + lane];
        float a1 = Wli1[t*64 + lane];
        float b0 = Wlm0[t*64 + lane];
        float b1 = Wlm1[t*64 + lane];
        f0  += xs  * a0;   m0  += xs  * b0;
        f1x += xv0 * a1;   f1y += xv1 * a1;   f1z += xv2 * a1;
        m1x += xv0 * b1;   m1y += xv1 * b1;   m1z += xv2 * b1;
    }

    const float a   = attr[n] * INV64;
    const float dis = 1.0f / sqrtf(deg[n]);
    const float fa  = a * dis;

    ushort4 pk;
    pk.x = f2bf(f0  * fa);
    pk.y = f2bf(f1x * fa);
    pk.z = f2bf(f1y * fa);
    pk.w = f2bf(f1z * fa);
    fvb[(size_t)n * 64 + lane] = pk;

    float* orow = out + (size_t)n * 256;
    orow[lane] = C_S * m0 * a;
    orow[64 + lane*3    ] = C_S * m1x * a;
    orow[64 + lane*3 + 1] = C_S * m1y * a;
    orow[64 + lane*3 + 2] = C_S * m1z * a;
}

// ---------------- weight prep: w2t[256][128], w1t[112][32] (bf16, scaled) ---
__global__ __launch_bounds__(256) void k_w2t(
    const float* __restrict__ W2, const float* __restrict__ W1,
    unsigned short* __restrict__ w2t, unsigned short* __restrict__ w1t)
{
    const int i = blockIdx.x * 256 + threadIdx.x;
    if (i < 32768) {
        const int n = i >> 7, k = i & 127;
        w2t[i] = (k < 100) ? f2bf(W2[k*256 + n] * SC2) : (unsigned short)0;
    } else if (i < 32768 + 3584) {
        const int j = i - 32768;
        const int n = j >> 5, k = j & 31;
        w1t[j] = (k < 10 && n < 100) ? f2bf(W1[k*100 + n] * INV1)
                                     : (unsigned short)0;
    }
}

// ---------------- counting sort by dst + sorted edge data -------------------
__global__ __launch_bounds__(256) void k_hist(const int* __restrict__ edst,
                                              int* __restrict__ hist) {
    const int e = blockIdx.x * 256 + threadIdx.x;
    if (e < N_EDGES) atomicAdd(&hist[edst[e]], 1);
}

__global__ __launch_bounds__(1024) void k_scan(const int* __restrict__ hist,
                                               int* __restrict__ starts,
                                               int* __restrict__ cursor) {
    __shared__ int part[1024];
    const int t = threadIdx.x;
    const int C = 20;
    const int base = t * C;
    int s = 0;
    for (int i = 0; i < C; ++i) {
        const int idx = base + i;
        if (idx < N_NODES) s += hist[idx];
    }
    part[t] = s;
    __syncthreads();
    for (int off = 1; off < 1024; off <<= 1) {
        int v = (t >= off) ? part[t - off] : 0;
        __syncthreads();
        part[t] += v;
        __syncthreads();
    }
    int run = part[t] - s;
    for (int i = 0; i < C; ++i) {
        const int idx = base + i;
        if (idx < N_NODES) {
            starts[idx] = run;
            cursor[idx] = run;
            run += hist[idx];
        }
    }
    if (t == 1023) starts[N_NODES] = N_EDGES;
}

__global__ __launch_bounds__(256) void k_scatter(
    const int* __restrict__ esrc, const int* __restrict__ edst,
    const float4* __restrict__ eattr4, const float* __restrict__ elen,
    int* __restrict__ cursor, int* __restrict__ esrc_s,
    float4* __restrict__ eattrs, unsigned short* __restrict__ elen_sb)
{
    const int e = blockIdx.x * 256 + threadIdx.x;
    if (e < N_EDGES) {
        const int p = atomicAdd(&cursor[edst[e]], 1);
        esrc_s[p] = esrc[e];
        eattrs[p] = eattr4[e];
        const float* el = elen + (size_t)e * 10;
        unsigned short v[32];
        #pragma unroll
        for (int b = 0; b < 10; ++b) v[b] = f2bf(el[b]);
        #pragma unroll
        for (int b = 10; b < 32; ++b) v[b] = 0;
        short8* dst = (short8*)(elen_sb + (size_t)p * 32);
        #pragma unroll
        for (int s = 0; s < 4; ++s) {
            short8 pk;
            #pragma unroll
            for (int j = 0; j < 8; ++j) pk[j] = (short)v[s*8 + j];
            dst[s] = pk;
        }
    }
}

// ---------------- edge MLP, MFMA, sorted in/out -----------------------------
// Change vs R7: copy-out to TWO arrays ewAB/ewCD (dword per channel each),
// fully coalesced 256 B/row stores (was: 8 B-stride dwords, 2x sector waste).
__global__ __launch_bounds__(256, 4) void k_mlp(
    const unsigned short* __restrict__ elen_sb,
    const unsigned short* __restrict__ w1t,
    const unsigned short* __restrict__ w2t,
    unsigned int* __restrict__ ewAB,
    unsigned int* __restrict__ ewCD)
{
    __shared__ unsigned short Hs[128 * 136];   // [e][k] stride 136
    const int t    = threadIdx.x;
    const int w    = t >> 6;
    const int lane = t & 63;
    const int m15  = lane & 15;
    const int q    = lane >> 4;
    const int eb   = w * 32;
    const int e0   = blockIdx.x * 128;

    {
        const int r = eb + (lane >> 1);
        const int c = 112 + (lane & 1) * 8;
        short8 z = {0,0,0,0,0,0,0,0};
        *(short8*)&Hs[r*136 + c] = z;
    }

    short8 xa0 = *(const short8*)(elen_sb + (size_t)(e0 + eb      + m15)*32 + q*8);
    short8 xa1 = *(const short8*)(elen_sb + (size_t)(e0 + eb + 16 + m15)*32 + q*8);

    for (int nt = 0; nt < 7; ++nt) {
        short8 bw = *(const short8*)(w1t + (nt*16 + m15)*32 + q*8);
        f32x4 z4 = {0.f, 0.f, 0.f, 0.f};
        f32x4 h0 = __builtin_amdgcn_mfma_f32_16x16x32_bf16(xa0, bw, z4, 0, 0, 0);
        f32x4 h1 = __builtin_amdgcn_mfma_f32_16x16x32_bf16(xa1, bw, z4, 0, 0, 0);
        #pragma unroll
        for (int r = 0; r < 4; ++r) {
            Hs[(eb      + q*4 + r)*136 + nt*16 + m15] = f2bf(silu_f(h0[r]));
            Hs[(eb + 16 + q*4 + r)*136 + nt*16 + m15] = f2bf(silu_f(h1[r]));
        }
    }
    // same-wave RAW on Hs -> compiler lgkmcnt, no barrier

    short8 A0[4], A1[4];
    #pragma unroll
    for (int s = 0; s < 4; ++s) {
        A0[s] = *(const short8*)&Hs[(eb      + m15)*136 + s*32 + q*8];
        A1[s] = *(const short8*)&Hs[(eb + 16 + m15)*136 + s*32 + q*8];
    }

    unsigned short* stg = &Hs[eb * 136];       // 32 rows x 136, per-wave
    #pragma unroll
    for (int half = 0; half < 2; ++half) {
        for (int nt8 = 0; nt8 < 8; ++nt8) {
            const int nt = half*8 + nt8;
            f32x4 c0 = {0.f,0.f,0.f,0.f}, c1 = {0.f,0.f,0.f,0.f};
            const unsigned short* bp = w2t + ((size_t)(nt*16 + m15) << 7);
            #pragma unroll
            for (int s = 0; s < 4; ++s) {
                short8 B = *(const short8*)(bp + s*32 + q*8);
                c0 = __builtin_amdgcn_mfma_f32_16x16x32_bf16(A0[s], B, c0, 0, 0, 0);
                c1 = __builtin_amdgcn_mfma_f32_16x16x32_bf16(A1[s], B, c1, 0, 0, 0);
            }
            #pragma unroll
            for (int r = 0; r < 4; ++r) {
                stg[(     q*4 + r)*136 + nt8*16 + m15] = f2bf(c0[r]);
                stg[(16 + q*4 + r)*136 + nt8*16 + m15] = f2bf(c1[r]);
            }
        }
        // coalesced copy-out: row r = edge (e0+eb+r); lane = channel.
        // stg col lane = first seg of this half, col 64+lane = second seg.
        // half0 -> (wa,wb) dword in ewAB; half1 -> (wc,wd) dword in ewCD.
        unsigned int* dstp = (half == 0) ? ewAB : ewCD;
        for (int r = 0; r < 32; ++r) {
            const unsigned int v =
                (unsigned int)stg[r*136 + lane] |
                ((unsigned int)stg[r*136 + 64 + lane] << 16);
            dstp[(size_t)(e0 + eb + r) * 64 + lane] = v;
        }
    }
}

// ---------------- per-dst gather + fused W_lo GEMM + epilogue ---------------
// (R7 fused version; weight read = 2 dwords from ewAB/ewCD)
__global__ __launch_bounds__(256) void k_gather(
    const int* __restrict__ starts, const int* __restrict__ esrc_s,
    const float4* __restrict__ eattrs,
    const unsigned int* __restrict__ ewAB,
    const unsigned int* __restrict__ ewCD,
    const ushort4* __restrict__ fvb,
    const float* __restrict__ attr, const float* __restrict__ deg,
    const float* __restrict__ Wlo0, const float* __restrict__ Wlo1,
    float* __restrict__ out)
{
    __shared__ float sm[4][512];
    const int wave = threadIdx.x >> 6;
    const int lane = threadIdx.x & 63;
    const int n = blockIdx.x * 4 + wave;

    const int beg = starts[n], end = starts[n + 1];
    float sA=0.f, sB=0.f;
    float vA0=0.f, vA1=0.f, vA2=0.f;
    float vB0=0.f, vB1=0.f, vB2=0.f;

    for (int base = beg; base < end; base += 64) {
        const int cnt = min(64, end - base);
        int    srcv = 0;
        float4 eav  = make_float4(0.f, 0.f, 0.f, 0.f);
        if (lane < cnt) {
            srcv = esrc_s[base + lane];
            eav  = eattrs[base + lane];
        }
        #pragma unroll 2
        for (int j = 0; j < cnt; ++j) {
            const int   src = __shfl(srcv, j);
            const float y0  = __shfl(eav.x, j);
            const float y10 = __shfl(eav.y, j);
            const float y11 = __shfl(eav.z, j);
            const float y12 = __shfl(eav.w, j);

            const unsigned int uab = ewAB[(size_t)(base + j)*64 + lane];
            const unsigned int ucd = ewCD[(size_t)(base + j)*64 + lane];
            const float wa = bf2f((unsigned short)(uab & 0xFFFFu));
            const float wb = bf2f((unsigned short)(uab >> 16));
            const float wc = bf2f((unsigned short)(ucd & 0xFFFFu));
            const float wd = bf2f((unsigned short)(ucd >> 16));

            const ushort4 g4 = fvb[(size_t)src * 64 + lane];
            const float g0  = bf2f(g4.x);
            const float g10 = bf2f(g4.y);
            const float g11 = bf2f(g4.z);
            const float g12 = bf2f(g4.w);

            const float dotv = g10*y10 + g11*y11 + g12*y12;
            sA += wa * g0 * y0;
            sB += wb * dotv;
            const float t0 = wc * g0;
            vA0 += t0 * y10;  vA1 += t0 * y11;  vA2 += t0 * y12;
            const float t1 = wd * y0;
            vB0 += t1 * g10;  vB1 += t1 * g11;  vB2 += t1 * g12;
        }
    }

    const float dis = 1.0f / sqrtf(deg[n]);
    sm[wave][lane            ] = sA * dis;
    sm[wave][64  + lane      ] = sB * IS3 * dis;
    sm[wave][128 + lane      ] = vA0 * dis;
    sm[wave][128 + 64 + lane ] = vB0 * dis;
    sm[wave][256 + lane      ] = vA1 * dis;
    sm[wave][256 + 64 + lane ] = vB1 * dis;
    sm[wave][384 + lane      ] = vA2 * dis;
    sm[wave][384 + 64 + lane ] = vB2 * dis;
    __syncthreads();

    float o0=0.f, o1x=0.f, o1y=0.f, o1z=0.f;
    #pragma unroll 4
    for (int c = 0; c < 128; ++c) {
        const float w0 = Wlo0[c*64 + lane];
        const float w1 = Wlo1[c*64 + lane];
        o0  += sm[wave][c]         * w0;
        o1x += sm[wave][128 + c]   * w1;
        o1y += sm[wave][256 + c]   * w1;
        o1z += sm[wave][384 + c]   * w1;
    }

    const float a = attr[n] * INVLO;
    float* orow = out + (size_t)n * 256;
    orow[lane] += C_X * o0 * a;
    orow[64 + lane*3    ] += C_X * o1x * a;
    orow[64 + lane*3 + 1] += C_X * o1y * a;
    orow[64 + lane*3 + 2] += C_X * o1z * a;
}

// ======================= fallback (round-1) path ============================
__global__ __launch_bounds__(256) void k_node_in_legacy(
    const float* __restrict__ ni, const float* __restrict__ attr,
    const float* __restrict__ deg,
    const float* __restrict__ Wli0, const float* __restrict__ Wli1,
    const float* __restrict__ Wlm0, const float* __restrict__ Wlm1,
    float* __restrict__ f, float* __restrict__ out)
{
    __shared__ float raw[4][256];
    const int wave = threadIdx.x >> 6;
    const int lane = threadIdx.x & 63;
    const int n = blockIdx.x * 4 + wave;

    const float* row = ni + (size_t)n * 256;
    raw[wave][lane      ] = row[lane      ];
    raw[wave][lane + 64 ] = row[lane + 64 ];
    raw[wave][lane + 128] = row[lane + 128];
    raw[wave][lane + 192] = row[lane + 192];
    __syncthreads();

    float f0 = 0.f, m0 = 0.f;
    float f1x = 0.f, f1y = 0.f, f1z = 0.f;
    float m1x = 0.f, m1y = 0.f, m1z = 0.f;
    for (int t = 0; t < 64; ++t) {
        float xs  = raw[wave][t];
        float xv0 = raw[wave][64 + t*3    ];
        float xv1 = raw[wave][64 + t*3 + 1];
        float xv2 = raw[wave][64 + t*3 + 2];
        float a0 = Wli0[t*64 + lane];
        float a1 = Wli1[t*64 + lane];
        float b0 = Wlm0[t*64 + lane];
        float b1 = Wlm1[t*64 + lane];
        f0  += xs  * a0;   m0  += xs  * b0;
        f1x += xv0 * a1;   f1y += xv1 * a1;   f1z += xv2 * a1;
        m1x += xv0 * b1;   m1y += xv1 * b1;   m1z += xv2 * b1;
    }

    const float a   = attr[n] * INV64;
    const float dis = 1.0f / sqrtf(deg[n]);
    const float fa  = a * dis;

    float* fr = f + (size_t)n * 256;
    fr[lane      ] = f0  * fa;
    fr[64  + lane] = f1x * fa;
    fr[128 + lane] = f1y * fa;
    fr[192 + lane] = f1z * fa;

    float* orow = out + (size_t)n * 256;
    orow[lane] = C_S * m0 * a;
    orow[64 + lane*3    ] = C_S * m1x * a;
    orow[64 + lane*3 + 1] = C_S * m1y * a;
    orow[64 + lane*3 + 2] = C_S * m1z * a;
}

__global__ __launch_bounds__(256) void k_edge_legacy(
    const float* __restrict__ eattr, const float* __restrict__ elen,
    const float* __restrict__ W1, const float* __restrict__ W2,
    const int* __restrict__ esrc, const int* __restrict__ edst,
    const float* __restrict__ f, float* __restrict__ acc)
{
    __shared__ float hsh[4][104];
    const int wave = threadIdx.x >> 6;
    const int lane = threadIdx.x & 63;
    const int e = blockIdx.x * 4 + wave;

    const float* el = elen + (size_t)e * 10;
    float elr[10];
    #pragma unroll
    for (int b = 0; b < 10; ++b) elr[b] = el[b];

    float a1 = 0.f;
    #pragma unroll
    for (int b = 0; b < 10; ++b) a1 += elr[b] * W1[b*100 + lane];
    hsh[wave][lane] = silu_f(a1 * INV1);
    if (lane < 36) {
        float a2 = 0.f;
        #pragma unroll
        for (int b = 0; b < 10; ++b) a2 += elr[b] * W1[b*100 + 64 + lane];
        hsh[wave][64 + lane] = silu_f(a2 * INV1);
    }
    __syncthreads();

    float wa = 0.f, wb = 0.f, wc = 0.f, wd = 0.f;
    for (int j = 0; j < 100; ++j) {
        float hj = hsh[wave][j];
        const float* wr = W2 + j*256;
        wa += hj * wr[lane      ];
        wb += hj * wr[64  + lane];
        wc += hj * wr[128 + lane];
        wd += hj * wr[192 + lane];
    }
    wa *= SC2; wb *= SC2; wc *= SC2; wd *= SC2;

    const int src = esrc[e];
    const int dst = edst[e];
    const float y0  = eattr[e*4 + 0];
    const float y10 = eattr[e*4 + 1];
    const float y11 = eattr[e*4 + 2];
    const float y12 = eattr[e*4 + 3];

    const float* fr = f + (size_t)src * 256;
    const float g0  = fr[lane      ];
    const float g10 = fr[64  + lane];
    const float g11 = fr[128 + lane];
    const float g12 = fr[192 + lane];

    const float dotv = g10*y10 + g11*y11 + g12*y12;

    float* ar = acc + (size_t)dst * 512;
    atomicAdd(ar + lane,                  wa * g0 * y0);
    atomicAdd(ar + 64 + lane,             wb * dotv * IS3);
    atomicAdd(ar + 128 +   0 + lane,      wc * g0 * y10);
    atomicAdd(ar + 128 + 128 + lane,      wc * g0 * y11);
    atomicAdd(ar + 128 + 256 + lane,      wc * g0 * y12);
    atomicAdd(ar + 128 +   0 + 64 + lane, wd * g10 * y0);
    atomicAdd(ar + 128 + 128 + 64 + lane, wd * g11 * y0);
    atomicAdd(ar + 128 + 256 + 64 + lane, wd * g12 * y0);
}

__global__ __launch_bounds__(256) void k_node_out_legacy(
    const float* __restrict__ acc, const float* __restrict__ attr,
    const float* __restrict__ deg, const float* __restrict__ Wlo0,
    const float* __restrict__ Wlo1, float* __restrict__ out)
{
    __shared__ float sm[4][512];
    const int wave = threadIdx.x >> 6;
    const int lane = threadIdx.x & 63;
    const int n = blockIdx.x * 4 + wave;

    const float dis = 1.0f / sqrtf(deg[n]);
    const float* ar = acc + (size_t)n * 512;
    for (int i = lane; i < 512; i += 64) sm[wave][i] = ar[i] * dis;
    __syncthreads();

    float o0 = 0.f, o1x = 0.f, o1y = 0.f, o1z = 0.f;
    for (int c = 0; c < 128; ++c) {
        float w0 = Wlo0[c*64 + lane];
        float w1 = Wlo1[c*64 + lane];
        o0  += sm[wave][c]        * w0;
        o1x += sm[wave][128 + c]  * w1;
        o1y += sm[wave][256 + c]  * w1;
        o1z += sm[wave][384 + c]  * w1;
    }

    const float a = attr[n] * INVLO;
    float* orow = out + (size_t)n * 256;
    orow[lane] += C_X * o0 * a;
    orow[64 + lane*3    ] += C_X * o1x * a;
    orow[64 + lane*3 + 1] += C_X * o1y * a;
    orow[64 + lane*3 + 2] += C_X * o1z * a;
}

// ============================================================================
extern "C" void kernel_launch(void* const* d_in, const int* in_sizes, int n_in,
                              void* d_out, int out_size, void* d_ws, size_t ws_size,
                              hipStream_t stream) {
    const float* ni    = (const float*)d_in[0];
    const float* attr  = (const float*)d_in[1];
    const float* deg   = (const float*)d_in[2];
    const float* eattr = (const float*)d_in[3];
    const float* elen  = (const float*)d_in[4];
    const float* Wli0  = (const float*)d_in[5];
    const float* Wli1  = (const float*)d_in[6];
    const float* Wlm0  = (const float*)d_in[7];
    const float* Wlm1  = (const float*)d_in[8];
    const float* Wm1   = (const float*)d_in[9];
    const float* Wm2   = (const float*)d_in[10];
    const float* Wlo0  = (const float*)d_in[11];
    const float* Wlo1  = (const float*)d_in[12];
    const int*   esrc  = (const int*)d_in[13];
    const int*   edst  = (const int*)d_in[14];

    float* out = (float*)d_out;

    // ws layout (fast path), 16 B-aligned sections
    char* wsb = (char*)d_ws;
    size_t off = 0;
    ushort4* fvb = (ushort4*)(wsb + off);               off += (size_t)N_NODES * 64 * 8;    // 10.24 MB
    unsigned int* ewAB = (unsigned int*)(wsb + off);    off += (size_t)N_EDGES * 64 * 4;    // 81.92 MB
    unsigned int* ewCD = (unsigned int*)(wsb + off);    off += (size_t)N_EDGES * 64 * 4;    // 81.92 MB
    unsigned short* elen_sb = (unsigned short*)(wsb + off); off += (size_t)N_EDGES * 32 * 2;// 20.48 MB
    float4* eattrs = (float4*)(wsb + off);              off += (size_t)N_EDGES * 16;        // 5.12 MB
    int* esrc_s = (int*)(wsb + off);                    off += (size_t)N_EDGES * 4;         // 1.28 MB
    unsigned short* w2t = (unsigned short*)(wsb + off); off += 32768 * 2;
    unsigned short* w1t = (unsigned short*)(wsb + off); off += 3584 * 2;
    int* starts = (int*)(wsb + off);                    off += (size_t)(N_NODES + 4) * 4;
    int* hist   = (int*)(wsb + off);                    off += (size_t)N_NODES * 4;
    int* cursor = (int*)(wsb + off);                    off += (size_t)N_NODES * 4;
    const size_t need_fast = off;

    if (ws_size >= need_fast) {
        hipMemsetAsync(hist, 0, (size_t)N_NODES * sizeof(int), stream);
        k_node_in<<<N_NODES / 4, 256, 0, stream>>>(ni, attr, deg, Wli0, Wli1,
                                                   Wlm0, Wlm1, fvb, out);
        k_w2t    <<<144, 256, 0, stream>>>(Wm2, Wm1, w2t, w1t);
        k_hist   <<<N_EDGES / 256, 256, 0, stream>>>(edst, hist);
        k_scan   <<<1, 1024, 0, stream>>>(hist, starts, cursor);
        k_scatter<<<N_EDGES / 256, 256, 0, stream>>>(esrc, edst,
                                                     (const float4*)eattr, elen,
                                                     cursor, esrc_s, eattrs, elen_sb);
        k_mlp    <<<N_EDGES / 128, 256, 0, stream>>>(elen_sb, w1t, w2t, ewAB, ewCD);
        k_gather <<<N_NODES / 4, 256, 0, stream>>>(starts, esrc_s, eattrs,
                                                   ewAB, ewCD, fvb, attr, deg,
                                                   Wlo0, Wlo1, out);
    } else {
        // fallback: round-1 atomic path (61.4 MB scratch)
        float* f   = (float*)d_ws;
        float* acc = f + (size_t)N_NODES * 256;
        hipMemsetAsync(acc, 0, (size_t)N_NODES * 512 * sizeof(float), stream);
        k_node_in_legacy<<<N_NODES / 4, 256, 0, stream>>>(ni, attr, deg, Wli0, Wli1,
                                                          Wlm0, Wlm1, f, out);
        k_edge_legacy<<<N_EDGES / 4, 256, 0, stream>>>(eattr, elen, Wm1, Wm2,
                                                       esrc, edst, f, acc);
        k_node_out_legacy<<<N_NODES / 4, 256, 0, stream>>>(acc, attr, deg,
                                                           Wlo0, Wlo1, out);
    }
}

// Round 10
// 409.567 us; speedup vs baseline: 1.1022x; 1.0098x over previous
//
#include <hip/hip_runtime.h>
#include <hip/hip_bf16.h>
#include <math.h>

#define N_NODES 20000
#define N_EDGES 320000

#define INV1   0.31622776601683794f   // 1/sqrt(10)
#define SC2    0.1f                   // 1/sqrt(100)
#define IS3    0.5773502691896258f    // 1/sqrt(3)
#define C_S    0.3826834323650898f    // sin(pi/8)
#define C_X    0.9238795325112867f    // cos(pi/8)
#define INV64  0.125f                 // 1/sqrt(64)
#define INVLO  0.08838834764831845f   // 1/sqrt(128)

typedef short     short8 __attribute__((ext_vector_type(8)));
typedef float     f32x4  __attribute__((ext_vector_type(4)));

__device__ __forceinline__ float silu_f(float x) {
    return x / (1.0f + expf(-x));
}
__device__ __forceinline__ unsigned short f2bf(float x) {
    __hip_bfloat16 h = __float2bfloat16(x);
    return *reinterpret_cast<unsigned short*>(&h);
}
__device__ __forceinline__ float bf2f(unsigned short u) {
    __hip_bfloat16 h;
    *reinterpret_cast<unsigned short*>(&h) = u;
    return __bfloat162float(h);
}

// ---------------- node pre-pass: fvb[n][64] = ushort4 bf16, out = c_s * m ---
__global__ __launch_bounds__(256) void k_node_in(
    const float* __restrict__ ni, const float* __restrict__ attr,
    const float* __restrict__ deg,
    const float* __restrict__ Wli0, const float* __restrict__ Wli1,
    const float* __restrict__ Wlm0, const float* __restrict__ Wlm1,
    ushort4* __restrict__ fvb, float* __restrict__ out)
{
    __shared__ float raw[4][256];
    const int wave = threadIdx.x >> 6;
    const int lane = threadIdx.x & 63;
    const int n = blockIdx.x * 4 + wave;

    const float* row = ni + (size_t)n * 256;
    raw[wave][lane      ] = row[lane      ];
    raw[wave][lane + 64 ] = row[lane + 64 ];
    raw[wave][lane + 128] = row[lane + 128];
    raw[wave][lane + 192] = row[lane + 192];
    __syncthreads();

    float f0 = 0.f, m0 = 0.f;
    float f1x = 0.f, f1y = 0.f, f1z = 0.f;
    float m1x = 0.f, m1y = 0.f, m1z = 0.f;
    #pragma unroll 4
    for (int t = 0; t < 64; ++t) {
        float xs  = raw[wave][t];
        float xv0 = raw[wave][64 + t*3    ];
        float xv1 = raw[wave][64 + t*3 + 1];
        float xv2 = raw[wave][64 + t*3 + 2];
        float a0 = Wli0[t*64 + lane];
        float a1 = Wli1[t*64 + lane];
        float b0 = Wlm0[t*64 + lane];
        float b1 = Wlm1[t*64 + lane];
        f0  += xs  * a0;   m0  += xs  * b0;
        f1x += xv0 * a1;   f1y += xv1 * a1;   f1z += xv2 * a1;
        m1x += xv0 * b1;   m1y += xv1 * b1;   m1z += xv2 * b1;
    }

    const float a   = attr[n] * INV64;
    const float dis = 1.0f / sqrtf(deg[n]);
    const float fa  = a * dis;

    ushort4 pk;
    pk.x = f2bf(f0  * fa);
    pk.y = f2bf(f1x * fa);
    pk.z = f2bf(f1y * fa);
    pk.w = f2bf(f1z * fa);
    fvb[(size_t)n * 64 + lane] = pk;

    float* orow = out + (size_t)n * 256;
    orow[lane] = C_S * m0 * a;
    orow[64 + lane*3    ] = C_S * m1x * a;
    orow[64 + lane*3 + 1] = C_S * m1y * a;
    orow[64 + lane*3 + 2] = C_S * m1z * a;
}

// ---------------- merged: hist (blocks 0..1249) + weight prep (1250..1393) --
__global__ __launch_bounds__(256) void k_prep(
    const int* __restrict__ edst, int* __restrict__ hist,
    const float* __restrict__ W2, const float* __restrict__ W1,
    unsigned short* __restrict__ w2t, unsigned short* __restrict__ w1t)
{
    const int b = blockIdx.x;
    if (b < N_EDGES / 256) {
        const int e = b * 256 + threadIdx.x;
        atomicAdd(&hist[edst[e]], 1);
    } else {
        const int i = (b - N_EDGES / 256) * 256 + threadIdx.x;
        if (i < 32768) {
            const int n = i >> 7, k = i & 127;
            w2t[i] = (k < 100) ? f2bf(W2[k*256 + n] * SC2) : (unsigned short)0;
        } else if (i < 32768 + 3584) {
            const int j = i - 32768;
            const int n = j >> 5, k = j & 31;
            w1t[j] = (k < 10 && n < 100) ? f2bf(W1[k*100 + n] * INV1)
                                         : (unsigned short)0;
        }
    }
}

__global__ __launch_bounds__(1024) void k_scan(const int* __restrict__ hist,
                                               int* __restrict__ starts,
                                               int* __restrict__ cursor) {
    __shared__ int part[1024];
    const int t = threadIdx.x;
    const int C = 20;
    const int base = t * C;
    int s = 0;
    for (int i = 0; i < C; ++i) {
        const int idx = base + i;
        if (idx < N_NODES) s += hist[idx];
    }
    part[t] = s;
    __syncthreads();
    for (int off = 1; off < 1024; off <<= 1) {
        int v = (t >= off) ? part[t - off] : 0;
        __syncthreads();
        part[t] += v;
        __syncthreads();
    }
    int run = part[t] - s;
    for (int i = 0; i < C; ++i) {
        const int idx = base + i;
        if (idx < N_NODES) {
            starts[idx] = run;
            cursor[idx] = run;
            run += hist[idx];
        }
    }
    if (t == 1023) starts[N_NODES] = N_EDGES;
}

__global__ __launch_bounds__(256) void k_scatter(
    const int* __restrict__ esrc, const int* __restrict__ edst,
    const float4* __restrict__ eattr4, const float* __restrict__ elen,
    int* __restrict__ cursor, int* __restrict__ esrc_s,
    float4* __restrict__ eattrs, unsigned short* __restrict__ elen_sb)
{
    const int e = blockIdx.x * 256 + threadIdx.x;
    if (e < N_EDGES) {
        const int p = atomicAdd(&cursor[edst[e]], 1);
        esrc_s[p] = esrc[e];
        eattrs[p] = eattr4[e];
        const float* el = elen + (size_t)e * 10;
        unsigned short v[32];
        #pragma unroll
        for (int b = 0; b < 10; ++b) v[b] = f2bf(el[b]);
        #pragma unroll
        for (int b = 10; b < 32; ++b) v[b] = 0;
        short8* dst = (short8*)(elen_sb + (size_t)p * 32);
        #pragma unroll
        for (int s = 0; s < 4; ++s) {
            short8 pk;
            #pragma unroll
            for (int j = 0; j < 8; ++j) pk[j] = (short)v[s*8 + j];
            dst[s] = pk;
        }
    }
}

// ---------------- edge MLP, MFMA, sorted in/out -----------------------------
// NEW epilogue: pair wa/wb (and wc/wd) tiles -> 4 independent MFMA chains,
// pack dwords in registers, store DIRECTLY to global (no LDS C-staging).
__global__ __launch_bounds__(256, 4) void k_mlp(
    const unsigned short* __restrict__ elen_sb,
    const unsigned short* __restrict__ w1t,
    const unsigned short* __restrict__ w2t,
    unsigned int* __restrict__ ewAB,
    unsigned int* __restrict__ ewCD)
{
    __shared__ unsigned short Hs[128 * 136];   // [e][k] stride 136
    const int t    = threadIdx.x;
    const int w    = t >> 6;
    const int lane = t & 63;
    const int m15  = lane & 15;
    const int q    = lane >> 4;
    const int eb   = w * 32;
    const int e0   = blockIdx.x * 128;

    {
        const int r = eb + (lane >> 1);
        const int c = 112 + (lane & 1) * 8;
        short8 z = {0,0,0,0,0,0,0,0};
        *(short8*)&Hs[r*136 + c] = z;
    }

    short8 xa0 = *(const short8*)(elen_sb + (size_t)(e0 + eb      + m15)*32 + q*8);
    short8 xa1 = *(const short8*)(elen_sb + (size_t)(e0 + eb + 16 + m15)*32 + q*8);

    for (int nt = 0; nt < 7; ++nt) {
        short8 bw = *(const short8*)(w1t + (nt*16 + m15)*32 + q*8);
        f32x4 z4 = {0.f, 0.f, 0.f, 0.f};
        f32x4 h0 = __builtin_amdgcn_mfma_f32_16x16x32_bf16(xa0, bw, z4, 0, 0, 0);
        f32x4 h1 = __builtin_amdgcn_mfma_f32_16x16x32_bf16(xa1, bw, z4, 0, 0, 0);
        #pragma unroll
        for (int r = 0; r < 4; ++r) {
            Hs[(eb      + q*4 + r)*136 + nt*16 + m15] = f2bf(silu_f(h0[r]));
            Hs[(eb + 16 + q*4 + r)*136 + nt*16 + m15] = f2bf(silu_f(h1[r]));
        }
    }
    // same-wave RAW on Hs -> compiler lgkmcnt, no barrier

    short8 A0[4], A1[4];
    #pragma unroll
    for (int s = 0; s < 4; ++s) {
        A0[s] = *(const short8*)&Hs[(eb      + m15)*136 + s*32 + q*8];
        A1[s] = *(const short8*)&Hs[(eb + 16 + m15)*136 + s*32 + q*8];
    }

    // grp 0: tiles (nt4, nt4+4)   = (wa, wb) -> ewAB
    // grp 1: tiles (nt4+8, nt4+12) = (wc, wd) -> ewCD
    // channel ch = nt4*16 + m15; dword = loCh | hiCh<<16, matching k_gather.
    #pragma unroll
    for (int grp = 0; grp < 2; ++grp) {
        unsigned int* dstp = (grp == 0) ? ewAB : ewCD;
        for (int nt4 = 0; nt4 < 4; ++nt4) {
            const int ntA = grp*8 + nt4;
            const int ntB = grp*8 + nt4 + 4;
            f32x4 ca0 = {0.f,0.f,0.f,0.f}, ca1 = {0.f,0.f,0.f,0.f};
            f32x4 cb0 = {0.f,0.f,0.f,0.f}, cb1 = {0.f,0.f,0.f,0.f};
            const unsigned short* bpA = w2t + ((size_t)(ntA*16 + m15) << 7);
            const unsigned short* bpB = w2t + ((size_t)(ntB*16 + m15) << 7);
            #pragma unroll
            for (int s = 0; s < 4; ++s) {
                short8 BA = *(const short8*)(bpA + s*32 + q*8);
                short8 BB = *(const short8*)(bpB + s*32 + q*8);
                ca0 = __builtin_amdgcn_mfma_f32_16x16x32_bf16(A0[s], BA, ca0, 0, 0, 0);
                ca1 = __builtin_amdgcn_mfma_f32_16x16x32_bf16(A1[s], BA, ca1, 0, 0, 0);
                cb0 = __builtin_amdgcn_mfma_f32_16x16x32_bf16(A0[s], BB, cb0, 0, 0, 0);
                cb1 = __builtin_amdgcn_mfma_f32_16x16x32_bf16(A1[s], BB, cb1, 0, 0, 0);
            }
            const int ch = nt4*16 + m15;
            #pragma unroll
            for (int r = 0; r < 4; ++r) {
                const unsigned int v0 =
                    (unsigned int)f2bf(ca0[r]) | ((unsigned int)f2bf(cb0[r]) << 16);
                const unsigned int v1 =
                    (unsigned int)f2bf(ca1[r]) | ((unsigned int)f2bf(cb1[r]) << 16);
                dstp[(size_t)(e0 + eb +      q*4 + r) * 64 + ch] = v0;
                dstp[(size_t)(e0 + eb + 16 + q*4 + r) * 64 + ch] = v1;
            }
        }
    }
}

// ---------------- per-dst gather + fused W_lo GEMM + epilogue ---------------
// (byte-identical to R9)
__global__ __launch_bounds__(256) void k_gather(
    const int* __restrict__ starts, const int* __restrict__ esrc_s,
    const float4* __restrict__ eattrs,
    const unsigned int* __restrict__ ewAB,
    const unsigned int* __restrict__ ewCD,
    const ushort4* __restrict__ fvb,
    const float* __restrict__ attr, const float* __restrict__ deg,
    const float* __restrict__ Wlo0, const float* __restrict__ Wlo1,
    float* __restrict__ out)
{
    __shared__ float sm[4][512];
    const int wave = threadIdx.x >> 6;
    const int lane = threadIdx.x & 63;
    const int n = blockIdx.x * 4 + wave;

    const int beg = starts[n], end = starts[n + 1];
    float sA=0.f, sB=0.f;
    float vA0=0.f, vA1=0.f, vA2=0.f;
    float vB0=0.f, vB1=0.f, vB2=0.f;

    for (int base = beg; base < end; base += 64) {
        const int cnt = min(64, end - base);
        int    srcv = 0;
        float4 eav  = make_float4(0.f, 0.f, 0.f, 0.f);
        if (lane < cnt) {
            srcv = esrc_s[base + lane];
            eav  = eattrs[base + lane];
        }
        #pragma unroll 2
        for (int j = 0; j < cnt; ++j) {
            const int   src = __shfl(srcv, j);
            const float y0  = __shfl(eav.x, j);
            const float y10 = __shfl(eav.y, j);
            const float y11 = __shfl(eav.z, j);
            const float y12 = __shfl(eav.w, j);

            const unsigned int uab = ewAB[(size_t)(base + j)*64 + lane];
            const unsigned int ucd = ewCD[(size_t)(base + j)*64 + lane];
            const float wa = bf2f((unsigned short)(uab & 0xFFFFu));
            const float wb = bf2f((unsigned short)(uab >> 16));
            const float wc = bf2f((unsigned short)(ucd & 0xFFFFu));
            const float wd = bf2f((unsigned short)(ucd >> 16));

            const ushort4 g4 = fvb[(size_t)src * 64 + lane];
            const float g0  = bf2f(g4.x);
            const float g10 = bf2f(g4.y);
            const float g11 = bf2f(g4.z);
            const float g12 = bf2f(g4.w);

            const float dotv = g10*y10 + g11*y11 + g12*y12;
            sA += wa * g0 * y0;
            sB += wb * dotv;
            const float t0 = wc * g0;
            vA0 += t0 * y10;  vA1 += t0 * y11;  vA2 += t0 * y12;
            const float t1 = wd * y0;
            vB0 += t1 * g10;  vB1 += t1 * g11;  vB2 += t1 * g12;
        }
    }

    const float dis = 1.0f / sqrtf(deg[n]);
    sm[wave][lane            ] = sA * dis;
    sm[wave][64  + lane      ] = sB * IS3 * dis;
    sm[wave][128 + lane      ] = vA0 * dis;
    sm[wave][128 + 64 + lane ] = vB0 * dis;
    sm[wave][256 + lane      ] = vA1 * dis;
    sm[wave][256 + 64 + lane ] = vB1 * dis;
    sm[wave][384 + lane      ] = vA2 * dis;
    sm[wave][384 + 64 + lane ] = vB2 * dis;
    __syncthreads();

    float o0=0.f, o1x=0.f, o1y=0.f, o1z=0.f;
    #pragma unroll 4
    for (int c = 0; c < 128; ++c) {
        const float w0 = Wlo0[c*64 + lane];
        const float w1 = Wlo1[c*64 + lane];
        o0  += sm[wave][c]         * w0;
        o1x += sm[wave][128 + c]   * w1;
        o1y += sm[wave][256 + c]   * w1;
        o1z += sm[wave][384 + c]   * w1;
    }

    const float a = attr[n] * INVLO;
    float* orow = out + (size_t)n * 256;
    orow[lane] += C_X * o0 * a;
    orow[64 + lane*3    ] += C_X * o1x * a;
    orow[64 + lane*3 + 1] += C_X * o1y * a;
    orow[64 + lane*3 + 2] += C_X * o1z * a;
}

// ======================= fallback (round-1) path ============================
__global__ __launch_bounds__(256) void k_node_in_legacy(
    const float* __restrict__ ni, const float* __restrict__ attr,
    const float* __restrict__ deg,
    const float* __restrict__ Wli0, const float* __restrict__ Wli1,
    const float* __restrict__ Wlm0, const float* __restrict__ Wlm1,
    float* __restrict__ f, float* __restrict__ out)
{
    __shared__ float raw[4][256];
    const int wave = threadIdx.x >> 6;
    const int lane = threadIdx.x & 63;
    const int n = blockIdx.x * 4 + wave;

    const float* row = ni + (size_t)n * 256;
    raw[wave][lane      ] = row[lane      ];
    raw[wave][lane + 64 ] = row[lane + 64 ];
    raw[wave][lane + 128] = row[lane + 128];
    raw[wave][lane + 192] = row[lane + 192];
    __syncthreads();

    float f0 = 0.f, m0 = 0.f;
    float f1x = 0.f, f1y = 0.f, f1z = 0.f;
    float m1x = 0.f, m1y = 0.f, m1z = 0.f;
    for (int t = 0; t < 64; ++t) {
        float xs  = raw[wave][t];
        float xv0 = raw[wave][64 + t*3    ];
        float xv1 = raw[wave][64 + t*3 + 1];
        float xv2 = raw[wave][64 + t*3 + 2];
        float a0 = Wli0[t*64 + lane];
        float a1 = Wli1[t*64 + lane];
        float b0 = Wlm0[t*64 + lane];
        float b1 = Wlm1[t*64 + lane];
        f0  += xs  * a0;   m0  += xs  * b0;
        f1x += xv0 * a1;   f1y += xv1 * a1;   f1z += xv2 * a1;
        m1x += xv0 * b1;   m1y += xv1 * b1;   m1z += xv2 * b1;
    }

    const float a   = attr[n] * INV64;
    const float dis = 1.0f / sqrtf(deg[n]);
    const float fa  = a * dis;

    float* fr = f + (size_t)n * 256;
    fr[lane      ] = f0  * fa;
    fr[64  + lane] = f1x * fa;
    fr[128 + lane] = f1y * fa;
    fr[192 + lane] = f1z * fa;

    float* orow = out + (size_t)n * 256;
    orow[lane] = C_S * m0 * a;
    orow[64 + lane*3    ] = C_S * m1x * a;
    orow[64 + lane*3 + 1] = C_S * m1y * a;
    orow[64 + lane*3 + 2] = C_S * m1z * a;
}

__global__ __launch_bounds__(256) void k_edge_legacy(
    const float* __restrict__ eattr, const float* __restrict__ elen,
    const float* __restrict__ W1, const float* __restrict__ W2,
    const int* __restrict__ esrc, const int* __restrict__ edst,
    const float* __restrict__ f, float* __restrict__ acc)
{
    __shared__ float hsh[4][104];
    const int wave = threadIdx.x >> 6;
    const int lane = threadIdx.x & 63;
    const int e = blockIdx.x * 4 + wave;

    const float* el = elen + (size_t)e * 10;
    float elr[10];
    #pragma unroll
    for (int b = 0; b < 10; ++b) elr[b] = el[b];

    float a1 = 0.f;
    #pragma unroll
    for (int b = 0; b < 10; ++b) a1 += elr[b] * W1[b*100 + lane];
    hsh[wave][lane] = silu_f(a1 * INV1);
    if (lane < 36) {
        float a2 = 0.f;
        #pragma unroll
        for (int b = 0; b < 10; ++b) a2 += elr[b] * W1[b*100 + 64 + lane];
        hsh[wave][64 + lane] = silu_f(a2 * INV1);
    }
    __syncthreads();

    float wa = 0.f, wb = 0.f, wc = 0.f, wd = 0.f;
    for (int j = 0; j < 100; ++j) {
        float hj = hsh[wave][j];
        const float* wr = W2 + j*256;
        wa += hj * wr[lane      ];
        wb += hj * wr[64  + lane];
        wc += hj * wr[128 + lane];
        wd += hj * wr[192 + lane];
    }
    wa *= SC2; wb *= SC2; wc *= SC2; wd *= SC2;

    const int src = esrc[e];
    const int dst = edst[e];
    const float y0  = eattr[e*4 + 0];
    const float y10 = eattr[e*4 + 1];
    const float y11 = eattr[e*4 + 2];
    const float y12 = eattr[e*4 + 3];

    const float* fr = f + (size_t)src * 256;
    const float g0  = fr[lane      ];
    const float g10 = fr[64  + lane];
    const float g11 = fr[128 + lane];
    const float g12 = fr[192 + lane];

    const float dotv = g10*y10 + g11*y11 + g12*y12;

    float* ar = acc + (size_t)dst * 512;
    atomicAdd(ar + lane,                  wa * g0 * y0);
    atomicAdd(ar + 64 + lane,             wb * dotv * IS3);
    atomicAdd(ar + 128 +   0 + lane,      wc * g0 * y10);
    atomicAdd(ar + 128 + 128 + lane,      wc * g0 * y11);
    atomicAdd(ar + 128 + 256 + lane,      wc * g0 * y12);
    atomicAdd(ar + 128 +   0 + 64 + lane, wd * g10 * y0);
    atomicAdd(ar + 128 + 128 + 64 + lane, wd * g11 * y0);
    atomicAdd(ar + 128 + 256 + 64 + lane, wd * g12 * y0);
}

__global__ __launch_bounds__(256) void k_node_out_legacy(
    const float* __restrict__ acc, const float* __restrict__ attr,
    const float* __restrict__ deg, const float* __restrict__ Wlo0,
    const float* __restrict__ Wlo1, float* __restrict__ out)
{
    __shared__ float sm[4][512];
    const int wave = threadIdx.x >> 6;
    const int lane = threadIdx.x & 63;
    const int n = blockIdx.x * 4 + wave;

    const float dis = 1.0f / sqrtf(deg[n]);
    const float* ar = acc + (size_t)n * 512;
    for (int i = lane; i < 512; i += 64) sm[wave][i] = ar[i] * dis;
    __syncthreads();

    float o0 = 0.f, o1x = 0.f, o1y = 0.f, o1z = 0.f;
    for (int c = 0; c < 128; ++c) {
        float w0 = Wlo0[c*64 + lane];
        float w1 = Wlo1[c*64 + lane];
        o0  += sm[wave][c]        * w0;
        o1x += sm[wave][128 + c]  * w1;
        o1y += sm[wave][256 + c]  * w1;
        o1z += sm[wave][384 + c]  * w1;
    }

    const float a = attr[n] * INVLO;
    float* orow = out + (size_t)n * 256;
    orow[lane] += C_X * o0 * a;
    orow[64 + lane*3    ] += C_X * o1x * a;
    orow[64 + lane*3 + 1] += C_X * o1y * a;
    orow[64 + lane*3 + 2] += C_X * o1z * a;
}

// ============================================================================
extern "C" void kernel_launch(void* const* d_in, const int* in_sizes, int n_in,
                              void* d_out, int out_size, void* d_ws, size_t ws_size,
                              hipStream_t stream) {
    const float* ni    = (const float*)d_in[0];
    const float* attr  = (const float*)d_in[1];
    const float* deg   = (const float*)d_in[2];
    const float* eattr = (const float*)d_in[3];
    const float* elen  = (const float*)d_in[4];
    const float* Wli0  = (const float*)d_in[5];
    const float* Wli1  = (const float*)d_in[6];
    const float* Wlm0  = (const float*)d_in[7];
    const float* Wlm1  = (const float*)d_in[8];
    const float* Wm1   = (const float*)d_in[9];
    const float* Wm2   = (const float*)d_in[10];
    const float* Wlo0  = (const float*)d_in[11];
    const float* Wlo1  = (const float*)d_in[12];
    const int*   esrc  = (const int*)d_in[13];
    const int*   edst  = (const int*)d_in[14];

    float* out = (float*)d_out;

    // ws layout (fast path), 16 B-aligned sections
    char* wsb = (char*)d_ws;
    size_t off = 0;
    ushort4* fvb = (ushort4*)(wsb + off);               off += (size_t)N_NODES * 64 * 8;    // 10.24 MB
    unsigned int* ewAB = (unsigned int*)(wsb + off);    off += (size_t)N_EDGES * 64 * 4;    // 81.92 MB
    unsigned int* ewCD = (unsigned int*)(wsb + off);    off += (size_t)N_EDGES * 64 * 4;    // 81.92 MB
    unsigned short* elen_sb = (unsigned short*)(wsb + off); off += (size_t)N_EDGES * 32 * 2;// 20.48 MB
    float4* eattrs = (float4*)(wsb + off);              off += (size_t)N_EDGES * 16;        // 5.12 MB
    int* esrc_s = (int*)(wsb + off);                    off += (size_t)N_EDGES * 4;         // 1.28 MB
    unsigned short* w2t = (unsigned short*)(wsb + off); off += 32768 * 2;
    unsigned short* w1t = (unsigned short*)(wsb + off); off += 3584 * 2;
    int* starts = (int*)(wsb + off);                    off += (size_t)(N_NODES + 4) * 4;
    int* hist   = (int*)(wsb + off);                    off += (size_t)N_NODES * 4;
    int* cursor = (int*)(wsb + off);                    off += (size_t)N_NODES * 4;
    const size_t need_fast = off;

    if (ws_size >= need_fast) {
        hipMemsetAsync(hist, 0, (size_t)N_NODES * sizeof(int), stream);
        k_node_in<<<N_NODES / 4, 256, 0, stream>>>(ni, attr, deg, Wli0, Wli1,
                                                   Wlm0, Wlm1, fvb, out);
        k_prep   <<<N_EDGES / 256 + 144, 256, 0, stream>>>(edst, hist,
                                                           Wm2, Wm1, w2t, w1t);
        k_scan   <<<1, 1024, 0, stream>>>(hist, starts, cursor);
        k_scatter<<<N_EDGES / 256, 256, 0, stream>>>(esrc, edst,
                                                     (const float4*)eattr, elen,
                                                     cursor, esrc_s, eattrs, elen_sb);
        k_mlp    <<<N_EDGES / 128, 256, 0, stream>>>(elen_sb, w1t, w2t, ewAB, ewCD);
        k_gather <<<N_NODES / 4, 256, 0, stream>>>(starts, esrc_s, eattrs,
                                                   ewAB, ewCD, fvb, attr, deg,
                                                   Wlo0, Wlo1, out);
    } else {
        // fallback: round-1 atomic path (61.4 MB scratch)
        float* f   = (float*)d_ws;
        float* acc = f + (size_t)N_NODES * 256;
        hipMemsetAsync(acc, 0, (size_t)N_NODES * 512 * sizeof(float), stream);
        k_node_in_legacy<<<N_NODES / 4, 256, 0, stream>>>(ni, attr, deg, Wli0, Wli1,
                                                          Wlm0, Wlm1, f, out);
        k_edge_legacy<<<N_EDGES / 4, 256, 0, stream>>>(eattr, elen, Wm1, Wm2,
                                                       esrc, edst, f, acc);
        k_node_out_legacy<<<N_NODES / 4, 256, 0, stream>>>(acc, attr, deg,
                                                           Wlo0, Wlo1, out);
    }
}